// Round 4
// baseline (119.699 us; speedup 1.0000x reference)
//
#include <hip/hip_runtime.h>

// Problem constants (from reference)
#define N_NODES 2048
#define C_CH    128
#define NIRR    9
#define E_EL    10
// dslot mapping: 0 -> l0 (d=0), 1..3 -> l1 (d=0..2)
//
// MFMA formulation: G[36] per (node,c) column = U_sym[36x219] . M[219] where
// M = monomials {x_p x_q x_i (165, p<=q<=i), x_p x_q (45), x_p (9)} + 5 pad.
// Row map (32 MFMA rows): 0-15 G3(ds*4+k), 16-27 G2(ds*3+k), 28-31 G1(ds<2).
// G1 rows for ds=2,3 (4 values) are done in VALU.
// K = 224 = 14 tiles of 16. Shape: mfma_f32_32x32x16_f16 (C/D layout
// verified m74/m101: col=lane&31, row=(reg&3)+8*(reg>>2)+4*(lane>>5)).
//
// R4: revert to R2's VERIFIED per-wave inner body (R3's merged K-loop failed
// correctness, mechanism undiagnosed -> shelved). Geometry change only:
// 8 nodes/block (block = 512 thr = 8 waves, wave = node, 4 sequential tiles),
// grid 256 (1 block/CU, tail-free). Epilogue reuses each lw float4 across
// 4 nodes (thread (p,t) -> nodes p,p+2,p+4,p+6): lw L2 traffic 256->128 MB.
// All epilogue arrays fully unrolled / static-indexed (no scratch).

#define NKT 14
#define UTAB_HALVES (NKT * 512)    // 7168

typedef _Float16 f16x8 __attribute__((ext_vector_type(8)));
typedef float   f32x16 __attribute__((ext_vector_type(16)));
typedef float   f32x4u __attribute__((ext_vector_type(4), aligned(4)));
typedef float   pf2    __attribute__((ext_vector_type(2)));

// Monomial index tables: M[k] = msk[k] * xv10[a]*xv10[b2]*xv10[c], xv10[9]=1.
struct MonoTab {
    unsigned char a[224], b2[224], c[224], msk[224];
};
constexpr MonoTab makeMono() {
    MonoTab m{};
    int s3 = 0;
    for (int p = 0; p < 9; p++)
        for (int q = p; q < 9; q++)
            for (int i = q; i < 9; i++) { m.a[s3] = p; m.b2[s3] = q; m.c[s3] = i; m.msk[s3] = 1; s3++; }
    int s2 = 0;
    for (int p = 0; p < 9; p++)
        for (int q = p; q < 9; q++) { m.a[165 + s2] = p; m.b2[165 + s2] = q; m.c[165 + s2] = 9; m.msk[165 + s2] = 1; s2++; }
    for (int p = 0; p < 9; p++) { m.a[210 + p] = p; m.b2[210 + p] = 9; m.c[210 + p] = 9; m.msk[210 + p] = 1; }
    for (int k = 219; k < 224; k++) { m.a[k] = 9; m.b2[k] = 9; m.c[k] = 9; m.msk[k] = 0; }
    return m;
}
constexpr MonoTab MT = makeMono();

// Build U_sym directly into the A-fragment layout (f16) + fp32 us1f table.
__global__ __launch_bounds__(256) void build_utab_kernel(
    const float* __restrict__ u3_l0, const float* __restrict__ u2_l0, const float* __restrict__ u1_l0,
    const float* __restrict__ u3_l1, const float* __restrict__ u2_l1, const float* __restrict__ u1_l1,
    _Float16* __restrict__ Utab, float* __restrict__ us1f)
{
    int t = blockIdx.x * 256 + threadIdx.x;
    if (t < UTAB_HALVES) {
        int kt = t / 512, idx = t % 512;
        int lane = idx >> 3, j = idx & 7;
        int m = lane & 31, g = lane >> 5;
        int k = kt * 16 + g * 8 + j;
        float v = 0.f;
        if (m < 16) {                       // G3 rows: ds*4+kk, k in [0,165)
            int ds = m >> 2, kk = m & 3;
            if (k < 165) {
                int pp = MT.a[k], qq = MT.b2[k], ii = MT.c[k];
                const float* u = (ds == 0) ? u3_l0 : (u3_l1 + (ds - 1) * 2916);
                int perm[6][3] = {{pp,qq,ii},{pp,ii,qq},{qq,pp,ii},{qq,ii,pp},{ii,pp,qq},{ii,qq,pp}};
                float acc = 0.f;
                #pragma unroll
                for (int w = 0; w < 6; w++)
                    acc += u[((perm[w][0] * 9 + perm[w][1]) * 9 + perm[w][2]) * 4 + kk];
                float mult = (pp == qq && qq == ii) ? 6.f : ((pp == qq || qq == ii) ? 2.f : 1.f);
                v = acc / mult;
            }
        } else if (m < 28) {                // G2 rows: ds*3+kk, k in [165,210)
            int r = m - 16, ds = r / 3, kk = r % 3;
            if (k >= 165 && k < 210) {
                int pp = MT.a[k], qq = MT.b2[k];
                const float* u = (ds == 0) ? u2_l0 : (u2_l1 + (ds - 1) * 243);
                float acc = u[(pp * 9 + qq) * 3 + kk] + u[(qq * 9 + pp) * 3 + kk];
                v = (pp == qq) ? acc * 0.5f : acc;
            }
        } else {                            // G1 rows ds in {0,1}: k in [210,219)
            int r = m - 28, ds = r >> 1, kk = r & 1;
            if (k >= 210 && k < 219) {
                int p = k - 210;
                v = (ds == 0) ? u1_l0[p * 2 + kk] : u1_l1[(0 * 9 + p) * 2 + kk];
            }
        }
        Utab[t] = (_Float16)v;
    } else if (t < UTAB_HALVES + 72) {
        int q = t - UTAB_HALVES;
        int ds = q / 18, rem = q % 18, p = rem >> 1, kk = rem & 1;
        us1f[q] = (ds == 0) ? u1_l0[p * 2 + kk] : u1_l1[((ds - 1) * 9 + p) * 2 + kk];
    }
}

// Fused MFMA contraction + o3.Linear + skip.
// Block = 512 threads (8 waves), 8 nodes: wave w -> node w, 4 sequential
// column-tiles per wave (R2's verified inner body).
__global__ __launch_bounds__(512, 4) void fused_kernel(
    const float* __restrict__ x, const float* __restrict__ y,
    const _Float16* __restrict__ Utab, const float* __restrict__ us1f,
    const float* __restrict__ w3_l0, const float* __restrict__ w2_l0, const float* __restrict__ w1_l0,
    const float* __restrict__ w3_l1, const float* __restrict__ w2_l1, const float* __restrict__ w1_l1,
    const float* __restrict__ lw0, const float* __restrict__ lw1,
    const float* __restrict__ sc, float* __restrict__ out)
{
    __shared__ float fs[8][4][132];   // [node][dslot][c]
    int tid = threadIdx.x;
    int lane = tid & 63;
    int wid = tid >> 6;               // 0..7
    int n = lane & 31, g = lane >> 5;
    int b0 = blockIdx.x * 8;
    int b = b0 + wid;                 // this wave's node

    const f16x8* U8 = (const f16x8*)Utab;

    // element index: wave-uniform (all lanes same node)
    int e = 0;
    #pragma unroll
    for (int k = 1; k < E_EL; k++)
        if (y[b * E_EL + k] > 0.5f) e = k;
    e = __builtin_amdgcn_readfirstlane(e);

    #pragma unroll 1
    for (int tl = 0; tl < 4; tl++) {
        int c = tl * 32 + n;
        const float* xp = x + ((size_t)b * C_CH + c) * NIRR;
        f32x4u xa = *(const f32x4u*)xp;
        f32x4u xb = *(const f32x4u*)(xp + 4);
        float xv10[10] = {xa[0], xa[1], xa[2], xa[3], xb[0], xb[1], xb[2], xb[3], xp[8], 1.f};

        f32x16 acc;
        #pragma unroll
        for (int z = 0; z < 16; z++) acc[z] = 0.f;

        #pragma unroll
        for (int kt = 0; kt < NKT; kt++) {
            f16x8 af = U8[kt * 64 + lane];
            float mf[8];
            if (g == 0) {
                #pragma unroll
                for (int j = 0; j < 8; j++) {
                    const int k = kt * 16 + j;
                    mf[j] = MT.msk[k] ? xv10[MT.a[k]] * xv10[MT.b2[k]] * xv10[MT.c[k]] : 0.f;
                }
            } else {
                #pragma unroll
                for (int j = 0; j < 8; j++) {
                    const int k = kt * 16 + 8 + j;
                    mf[j] = MT.msk[k] ? xv10[MT.a[k]] * xv10[MT.b2[k]] * xv10[MT.c[k]] : 0.f;
                }
            }
            f16x8 bf;
            #pragma unroll
            for (int j = 0; j < 8; j++) bf[j] = (_Float16)mf[j];
            acc = __builtin_amdgcn_mfma_f32_32x32x16_f16(af, bf, acc, 0, 0, 0);
        }

        // G1 rows for ds=2,3 via VALU (wave-uniform us1f -> s_loads, hoistable)
        float G1hi[4];
        #pragma unroll
        for (int dd = 0; dd < 2; dd++) {
            #pragma unroll
            for (int kk = 0; kk < 2; kk++) {
                float a = 0.f;
                #pragma unroll
                for (int p = 0; p < 9; p++)
                    a += us1f[(2 + dd) * 18 + p * 2 + kk] * xv10[p];
                G1hi[dd * 2 + kk] = a;
            }
        }

        // Per-half partial w-contract directly from acc.
        // Lane holds rows row=(reg&3)+8*(reg>>2)+4*g:
        //  g=0: {0-3, 8-11, 16-19, 24-27}   g=1: {4-7, 12-15, 20-23, 28-31}
        float p0, p1, p2, p3;
        if (g == 0) {
            // f0: G3 rows 0-3 (regs 0-3) + G2 rows 16-18 (regs 8-10)
            p0 = 0.f;
            #pragma unroll
            for (int kk = 0; kk < 4; kk++) p0 += w3_l0[(e * 4 + kk) * 128 + c] * acc[kk];
            #pragma unroll
            for (int kk = 0; kk < 3; kk++) p0 += w2_l0[(e * 3 + kk) * 128 + c] * acc[8 + kk];
            // f1: G2 row 19 (reg 11)
            p1 = w2_l1[(e * 3 + 0) * 128 + c] * acc[11];
            // f2: G3 rows 8-11 (regs 4-7) + G2 row 24 (reg 12)
            p2 = 0.f;
            #pragma unroll
            for (int kk = 0; kk < 4; kk++) p2 += w3_l1[(e * 4 + kk) * 128 + c] * acc[4 + kk];
            p2 += w2_l1[(e * 3 + 2) * 128 + c] * acc[12];
            // f3: G2 rows 25-27 (regs 13-15) + G1(ds=3) via VALU
            p3 = 0.f;
            #pragma unroll
            for (int kk = 0; kk < 3; kk++) p3 += w2_l1[(e * 3 + kk) * 128 + c] * acc[13 + kk];
            #pragma unroll
            for (int kk = 0; kk < 2; kk++) p3 += w1_l1[(e * 2 + kk) * 128 + c] * G1hi[2 + kk];
        } else {
            // f0: G1 rows 28,29 (regs 12,13)
            p0 = w1_l0[(e * 2 + 0) * 128 + c] * acc[12]
               + w1_l0[(e * 2 + 1) * 128 + c] * acc[13];
            // f1: G3 rows 4-7 (regs 0-3) + G2 rows 20,21 (regs 8,9) + G1 rows 30,31 (regs 14,15)
            p1 = 0.f;
            #pragma unroll
            for (int kk = 0; kk < 4; kk++) p1 += w3_l1[(e * 4 + kk) * 128 + c] * acc[kk];
            p1 += w2_l1[(e * 3 + 1) * 128 + c] * acc[8];
            p1 += w2_l1[(e * 3 + 2) * 128 + c] * acc[9];
            #pragma unroll
            for (int kk = 0; kk < 2; kk++) p1 += w1_l1[(e * 2 + kk) * 128 + c] * acc[14 + kk];
            // f2: G2 rows 22,23 (regs 10,11) + G1(ds=2) via VALU
            p2 = w2_l1[(e * 3 + 0) * 128 + c] * acc[10]
               + w2_l1[(e * 3 + 1) * 128 + c] * acc[11];
            #pragma unroll
            for (int kk = 0; kk < 2; kk++) p2 += w1_l1[(e * 2 + kk) * 128 + c] * G1hi[kk];
            // f3: G3 rows 12-15 (regs 4-7)
            p3 = 0.f;
            #pragma unroll
            for (int kk = 0; kk < 4; kk++) p3 += w3_l1[(e * 4 + kk) * 128 + c] * acc[4 + kk];
        }
        float f0 = p0 + __shfl_xor(p0, 32, 64);
        float f1 = p1 + __shfl_xor(p1, 32, 64);
        float f2 = p2 + __shfl_xor(p2, 32, 64);
        float f3 = p3 + __shfl_xor(p3, 32, 64);

        if (g == 0) {
            fs[wid][0][c] = f0;
            fs[wid][1][c] = f1;
        } else {
            fs[wid][2][c] = f2;
            fs[wid][3][c] = f3;
        }
    }
    __syncthreads();

    // ---- o3.Linear + skip on threads 0..255: thread (p, t) owns 4 j-cols for
    // 4 nodes (p, p+2, p+4, p+6), reusing each lw float4 load across all 4 ----
    if (tid < 256) {
        int p = tid >> 7;
        int t = tid & 127;
        int sel, m = 0, j0;
        const float4* W4;
        bool isl0 = (t < 32);
        if (isl0) { sel = 0; j0 = 4 * t; W4 = (const float4*)lw0; }
        else {
            int idx = t - 32;
            m = idx >> 5;
            j0 = 4 * (idx & 31);
            sel = 1 + m;
            W4 = (const float4*)lw1;
        }
        int wbase = j0 >> 2;

        pf2 a01[4], a23[4];
        #pragma unroll
        for (int k = 0; k < 4; k++) {
            a01[k][0] = 0.f; a01[k][1] = 0.f;
            a23[k][0] = 0.f; a23[k][1] = 0.f;
        }

        #pragma unroll 4
        for (int ib = 0; ib < 32; ib++) {
            float fr[4][4];
            #pragma unroll
            for (int k = 0; k < 4; k++) {
                float4 f = *(const float4*)&fs[p + 2 * k][sel][4 * ib];
                fr[k][0] = f.x; fr[k][1] = f.y; fr[k][2] = f.z; fr[k][3] = f.w;
            }
            #pragma unroll
            for (int r = 0; r < 4; r++) {
                float4 w = W4[(4 * ib + r) * 32 + wbase];
                pf2 wlo = {w.x, w.y};
                pf2 whi = {w.z, w.w};
                #pragma unroll
                for (int k = 0; k < 4; k++) {
                    pf2 fk = {fr[k][r], fr[k][r]};
                    a01[k] = __builtin_elementwise_fma(wlo, fk, a01[k]);
                    a23[k] = __builtin_elementwise_fma(whi, fk, a23[k]);
                }
            }
        }
        const float inv_sqrt_c = 0.08838834764831845f;  // 1/sqrt(128)

        #pragma unroll
        for (int k = 0; k < 4; k++) {
            int bb = b0 + p + 2 * k;
            float a0 = a01[k][0], a1 = a01[k][1], a2 = a23[k][0], a3 = a23[k][1];
            if (isl0) {
                size_t o = (size_t)bb * 512 + j0;
                float4 s = *(const float4*)(sc + o);
                float4 rr;
                rr.x = a0 * inv_sqrt_c + s.x;
                rr.y = a1 * inv_sqrt_c + s.y;
                rr.z = a2 * inv_sqrt_c + s.z;
                rr.w = a3 * inv_sqrt_c + s.w;
                *(float4*)(out + o) = rr;
            } else {
                float av[4] = {a0, a1, a2, a3};
                #pragma unroll
                for (int jj = 0; jj < 4; jj++) {
                    size_t o = (size_t)bb * 512 + 128 + 3 * (j0 + jj) + m;
                    out[o] = av[jj] * inv_sqrt_c + sc[o];
                }
            }
        }
    }
}

extern "C" void kernel_launch(void* const* d_in, const int* in_sizes, int n_in,
                              void* d_out, int out_size, void* d_ws, size_t ws_size,
                              hipStream_t stream) {
    const float* x     = (const float*)d_in[0];
    const float* y     = (const float*)d_in[1];
    const float* sc    = (const float*)d_in[2];
    const float* u3_l0 = (const float*)d_in[3];
    const float* u2_l0 = (const float*)d_in[4];
    const float* u1_l0 = (const float*)d_in[5];
    const float* w3_l0 = (const float*)d_in[6];
    const float* w2_l0 = (const float*)d_in[7];
    const float* w1_l0 = (const float*)d_in[8];
    const float* u3_l1 = (const float*)d_in[9];
    const float* u2_l1 = (const float*)d_in[10];
    const float* u1_l1 = (const float*)d_in[11];
    const float* w3_l1 = (const float*)d_in[12];
    const float* w2_l1 = (const float*)d_in[13];
    const float* w1_l1 = (const float*)d_in[14];
    const float* lw0   = (const float*)d_in[15];
    const float* lw1   = (const float*)d_in[16];
    float* out = (float*)d_out;

    // Workspace: Utab (f16, 14336 B) | us1f (fp32, 288 B)
    _Float16* Utab = (_Float16*)d_ws;
    float* us1f = (float*)((char*)d_ws + UTAB_HALVES * 2);

    build_utab_kernel<<<(UTAB_HALVES + 72 + 255) / 256, 256, 0, stream>>>(
        u3_l0, u2_l0, u1_l0, u3_l1, u2_l1, u1_l1, Utab, us1f);
    fused_kernel<<<N_NODES / 8, 512, 0, stream>>>(
        x, y, Utab, us1f,
        w3_l0, w2_l0, w1_l0, w3_l1, w2_l1, w1_l1,
        lw0, lw1, sc, out);
}

// Round 5
// 115.685 us; speedup vs baseline: 1.0347x; 1.0347x over previous
//
#include <hip/hip_runtime.h>

// Problem constants (from reference)
#define N_NODES 2048
#define C_CH    128
#define NIRR    9
#define E_EL    10
// dslot mapping: 0 -> l0 (d=0), 1..3 -> l1 (d=0..2)
//
// MFMA formulation: G[36] per (node,c) column = U_sym[36x219] . M[219] where
// M = monomials {x_p x_q x_i (165, p<=q<=i), x_p x_q (45), x_p (9)} + 5 pad.
// Row map (32 MFMA rows): 0-15 G3(ds*4+k), 16-27 G2(ds*3+k), 28-31 G1(ds<2).
// G1 rows for ds=2,3 (4 values) are done in VALU.
// K = 224 = 14 tiles of 16. Shape: mfma_f32_32x32x16_f16 (C/D layout
// verified m74/m101: col=lane&31, row=(reg&3)+8*(reg>>2)+4*(lane>>5)).
//
// R5 = R1 geometry (4 nodes/block, 256 thr, grid 512, 2 blocks/CU — the
// verified best) + two verified work-reductions:
//  1) R2's partial w-contract (verified in R2): per-half partial sums from acc,
//     ONE shfl_xor(32) per dslot (4/tile vs 16), 27 weight loads/tile (vs 36),
//     no G[32] array.
//  2) A-fragment hoist: all 4 tiles share U8[kt*64+lane]; afv[14] kept in
//     registers (static-indexed, ~56 VGPR; (256,2) allows 256) — saves 42 L2
//     loads/wave. Pure CSE, no arithmetic change.
// R4's 8-node geometry regressed (spill-capped epilogue / 1 block-per-CU
// overlap loss) -> abandoned.

#define NKT 14
#define UTAB_HALVES (NKT * 512)    // 7168

typedef _Float16 f16x8 __attribute__((ext_vector_type(8)));
typedef float   f32x16 __attribute__((ext_vector_type(16)));
typedef float   f32x4u __attribute__((ext_vector_type(4), aligned(4)));
typedef float   pf2    __attribute__((ext_vector_type(2)));

// Monomial index tables: M[k] = msk[k] * xv10[a]*xv10[b2]*xv10[c], xv10[9]=1.
struct MonoTab {
    unsigned char a[224], b2[224], c[224], msk[224];
};
constexpr MonoTab makeMono() {
    MonoTab m{};
    int s3 = 0;
    for (int p = 0; p < 9; p++)
        for (int q = p; q < 9; q++)
            for (int i = q; i < 9; i++) { m.a[s3] = p; m.b2[s3] = q; m.c[s3] = i; m.msk[s3] = 1; s3++; }
    int s2 = 0;
    for (int p = 0; p < 9; p++)
        for (int q = p; q < 9; q++) { m.a[165 + s2] = p; m.b2[165 + s2] = q; m.c[165 + s2] = 9; m.msk[165 + s2] = 1; s2++; }
    for (int p = 0; p < 9; p++) { m.a[210 + p] = p; m.b2[210 + p] = 9; m.c[210 + p] = 9; m.msk[210 + p] = 1; }
    for (int k = 219; k < 224; k++) { m.a[k] = 9; m.b2[k] = 9; m.c[k] = 9; m.msk[k] = 0; }
    return m;
}
constexpr MonoTab MT = makeMono();

// Build U_sym directly into the A-fragment layout (f16) + fp32 us1f table.
__global__ __launch_bounds__(256) void build_utab_kernel(
    const float* __restrict__ u3_l0, const float* __restrict__ u2_l0, const float* __restrict__ u1_l0,
    const float* __restrict__ u3_l1, const float* __restrict__ u2_l1, const float* __restrict__ u1_l1,
    _Float16* __restrict__ Utab, float* __restrict__ us1f)
{
    int t = blockIdx.x * 256 + threadIdx.x;
    if (t < UTAB_HALVES) {
        int kt = t / 512, idx = t % 512;
        int lane = idx >> 3, j = idx & 7;
        int m = lane & 31, g = lane >> 5;
        int k = kt * 16 + g * 8 + j;
        float v = 0.f;
        if (m < 16) {                       // G3 rows: ds*4+kk, k in [0,165)
            int ds = m >> 2, kk = m & 3;
            if (k < 165) {
                int pp = MT.a[k], qq = MT.b2[k], ii = MT.c[k];
                const float* u = (ds == 0) ? u3_l0 : (u3_l1 + (ds - 1) * 2916);
                int perm[6][3] = {{pp,qq,ii},{pp,ii,qq},{qq,pp,ii},{qq,ii,pp},{ii,pp,qq},{ii,qq,pp}};
                float acc = 0.f;
                #pragma unroll
                for (int w = 0; w < 6; w++)
                    acc += u[((perm[w][0] * 9 + perm[w][1]) * 9 + perm[w][2]) * 4 + kk];
                float mult = (pp == qq && qq == ii) ? 6.f : ((pp == qq || qq == ii) ? 2.f : 1.f);
                v = acc / mult;
            }
        } else if (m < 28) {                // G2 rows: ds*3+kk, k in [165,210)
            int r = m - 16, ds = r / 3, kk = r % 3;
            if (k >= 165 && k < 210) {
                int pp = MT.a[k], qq = MT.b2[k];
                const float* u = (ds == 0) ? u2_l0 : (u2_l1 + (ds - 1) * 243);
                float acc = u[(pp * 9 + qq) * 3 + kk] + u[(qq * 9 + pp) * 3 + kk];
                v = (pp == qq) ? acc * 0.5f : acc;
            }
        } else {                            // G1 rows ds in {0,1}: k in [210,219)
            int r = m - 28, ds = r >> 1, kk = r & 1;
            if (k >= 210 && k < 219) {
                int p = k - 210;
                v = (ds == 0) ? u1_l0[p * 2 + kk] : u1_l1[(0 * 9 + p) * 2 + kk];
            }
        }
        Utab[t] = (_Float16)v;
    } else if (t < UTAB_HALVES + 72) {
        int q = t - UTAB_HALVES;
        int ds = q / 18, rem = q % 18, p = rem >> 1, kk = rem & 1;
        us1f[q] = (ds == 0) ? u1_l0[p * 2 + kk] : u1_l1[((ds - 1) * 9 + p) * 2 + kk];
    }
}

// Fused MFMA contraction + o3.Linear + skip. Block = 256 threads (4 waves),
// 4 nodes (one node per wave, 4 sequential tiles of 32 columns per wave).
__global__ __launch_bounds__(256, 2) void fused_kernel(
    const float* __restrict__ x, const float* __restrict__ y,
    const _Float16* __restrict__ Utab, const float* __restrict__ us1f,
    const float* __restrict__ w3_l0, const float* __restrict__ w2_l0, const float* __restrict__ w1_l0,
    const float* __restrict__ w3_l1, const float* __restrict__ w2_l1, const float* __restrict__ w1_l1,
    const float* __restrict__ lw0, const float* __restrict__ lw1,
    const float* __restrict__ sc, float* __restrict__ out)
{
    __shared__ float fs[4][4][132];   // [node][dslot][c]
    int tid = threadIdx.x;
    int lane = tid & 63;
    int wid = tid >> 6;               // 0..3
    int n = lane & 31, g = lane >> 5;
    int b0 = blockIdx.x * 4;
    int b = b0 + wid;                 // this wave's node

    const f16x8* U8 = (const f16x8*)Utab;

    // element index: wave-uniform (all lanes same node)
    int e = 0;
    #pragma unroll
    for (int k = 1; k < E_EL; k++)
        if (y[b * E_EL + k] > 0.5f) e = k;
    e = __builtin_amdgcn_readfirstlane(e);

    // A-fragments hoisted: tile-invariant, loaded once per wave (static idx)
    f16x8 afv[NKT];
    #pragma unroll
    for (int kt = 0; kt < NKT; kt++) afv[kt] = U8[kt * 64 + lane];

    #pragma unroll 1
    for (int tl = 0; tl < 4; tl++) {
        int c = tl * 32 + n;
        const float* xp = x + ((size_t)b * C_CH + c) * NIRR;
        f32x4u xa = *(const f32x4u*)xp;
        f32x4u xb = *(const f32x4u*)(xp + 4);
        float xv10[10] = {xa[0], xa[1], xa[2], xa[3], xb[0], xb[1], xb[2], xb[3], xp[8], 1.f};

        f32x16 acc;
        #pragma unroll
        for (int z = 0; z < 16; z++) acc[z] = 0.f;

        #pragma unroll
        for (int kt = 0; kt < NKT; kt++) {
            float mf[8];
            if (g == 0) {
                #pragma unroll
                for (int j = 0; j < 8; j++) {
                    const int k = kt * 16 + j;
                    mf[j] = MT.msk[k] ? xv10[MT.a[k]] * xv10[MT.b2[k]] * xv10[MT.c[k]] : 0.f;
                }
            } else {
                #pragma unroll
                for (int j = 0; j < 8; j++) {
                    const int k = kt * 16 + 8 + j;
                    mf[j] = MT.msk[k] ? xv10[MT.a[k]] * xv10[MT.b2[k]] * xv10[MT.c[k]] : 0.f;
                }
            }
            f16x8 bf;
            #pragma unroll
            for (int j = 0; j < 8; j++) bf[j] = (_Float16)mf[j];
            acc = __builtin_amdgcn_mfma_f32_32x32x16_f16(afv[kt], bf, acc, 0, 0, 0);
        }

        // G1 rows for ds=2,3 via VALU (wave-uniform us1f -> s_loads)
        float G1hi[4];
        #pragma unroll
        for (int dd = 0; dd < 2; dd++) {
            #pragma unroll
            for (int kk = 0; kk < 2; kk++) {
                float a = 0.f;
                #pragma unroll
                for (int p = 0; p < 9; p++)
                    a += us1f[(2 + dd) * 18 + p * 2 + kk] * xv10[p];
                G1hi[dd * 2 + kk] = a;
            }
        }

        // Per-half partial w-contract directly from acc (verified in R2).
        // Lane holds rows row=(reg&3)+8*(reg>>2)+4*g:
        //  g=0: {0-3, 8-11, 16-19, 24-27}   g=1: {4-7, 12-15, 20-23, 28-31}
        float p0, p1, p2, p3;
        if (g == 0) {
            // f0: G3 rows 0-3 (regs 0-3) + G2 rows 16-18 (regs 8-10)
            p0 = 0.f;
            #pragma unroll
            for (int kk = 0; kk < 4; kk++) p0 += w3_l0[(e * 4 + kk) * 128 + c] * acc[kk];
            #pragma unroll
            for (int kk = 0; kk < 3; kk++) p0 += w2_l0[(e * 3 + kk) * 128 + c] * acc[8 + kk];
            // f1: G2 row 19 (reg 11)
            p1 = w2_l1[(e * 3 + 0) * 128 + c] * acc[11];
            // f2: G3 rows 8-11 (regs 4-7) + G2 row 24 (reg 12)
            p2 = 0.f;
            #pragma unroll
            for (int kk = 0; kk < 4; kk++) p2 += w3_l1[(e * 4 + kk) * 128 + c] * acc[4 + kk];
            p2 += w2_l1[(e * 3 + 2) * 128 + c] * acc[12];
            // f3: G2 rows 25-27 (regs 13-15) + G1(ds=3) via VALU
            p3 = 0.f;
            #pragma unroll
            for (int kk = 0; kk < 3; kk++) p3 += w2_l1[(e * 3 + kk) * 128 + c] * acc[13 + kk];
            #pragma unroll
            for (int kk = 0; kk < 2; kk++) p3 += w1_l1[(e * 2 + kk) * 128 + c] * G1hi[2 + kk];
        } else {
            // f0: G1 rows 28,29 (regs 12,13)
            p0 = w1_l0[(e * 2 + 0) * 128 + c] * acc[12]
               + w1_l0[(e * 2 + 1) * 128 + c] * acc[13];
            // f1: G3 rows 4-7 (regs 0-3) + G2 rows 20,21 (regs 8,9) + G1 rows 30,31 (regs 14,15)
            p1 = 0.f;
            #pragma unroll
            for (int kk = 0; kk < 4; kk++) p1 += w3_l1[(e * 4 + kk) * 128 + c] * acc[kk];
            p1 += w2_l1[(e * 3 + 1) * 128 + c] * acc[8];
            p1 += w2_l1[(e * 3 + 2) * 128 + c] * acc[9];
            #pragma unroll
            for (int kk = 0; kk < 2; kk++) p1 += w1_l1[(e * 2 + kk) * 128 + c] * acc[14 + kk];
            // f2: G2 rows 22,23 (regs 10,11) + G1(ds=2) via VALU
            p2 = w2_l1[(e * 3 + 0) * 128 + c] * acc[10]
               + w2_l1[(e * 3 + 1) * 128 + c] * acc[11];
            #pragma unroll
            for (int kk = 0; kk < 2; kk++) p2 += w1_l1[(e * 2 + kk) * 128 + c] * G1hi[kk];
            // f3: G3 rows 12-15 (regs 4-7)
            p3 = 0.f;
            #pragma unroll
            for (int kk = 0; kk < 4; kk++) p3 += w3_l1[(e * 4 + kk) * 128 + c] * acc[4 + kk];
        }
        float f0 = p0 + __shfl_xor(p0, 32, 64);
        float f1 = p1 + __shfl_xor(p1, 32, 64);
        float f2 = p2 + __shfl_xor(p2, 32, 64);
        float f3 = p3 + __shfl_xor(p3, 32, 64);

        if (g == 0) {
            fs[wid][0][c] = f0;
            fs[wid][1][c] = f1;
        } else {
            fs[wid][2][c] = f2;
            fs[wid][3][c] = f3;
        }
    }
    __syncthreads();

    // ---- o3.Linear + skip: thread (p, t) owns 4 j-cols for 2 nodes (p, p+2),
    // reusing each lw float4 load across both nodes (R1-verbatim) ----
    {
        int p = tid >> 7;
        int t = tid & 127;
        int sel, m = 0, j0;
        const float4* W4;
        bool isl0 = (t < 32);
        if (isl0) { sel = 0; j0 = 4 * t; W4 = (const float4*)lw0; }
        else {
            int idx = t - 32;
            m = idx >> 5;
            j0 = 4 * (idx & 31);
            sel = 1 + m;
            W4 = (const float4*)lw1;
        }
        int wbase = j0 >> 2;

        pf2 a01A = {0.f, 0.f}, a23A = {0.f, 0.f};
        pf2 a01B = {0.f, 0.f}, a23B = {0.f, 0.f};
        #pragma unroll 4
        for (int ib = 0; ib < 32; ib++) {
            float4 fA = *(const float4*)&fs[p][sel][4 * ib];
            float4 fB = *(const float4*)&fs[p + 2][sel][4 * ib];
            float frA[4] = {fA.x, fA.y, fA.z, fA.w};
            float frB[4] = {fB.x, fB.y, fB.z, fB.w};
            #pragma unroll
            for (int r = 0; r < 4; r++) {
                float4 w = W4[(4 * ib + r) * 32 + wbase];
                pf2 wlo = {w.x, w.y};
                pf2 whi = {w.z, w.w};
                pf2 fra = {frA[r], frA[r]};
                pf2 frb = {frB[r], frB[r]};
                a01A = __builtin_elementwise_fma(wlo, fra, a01A);
                a23A = __builtin_elementwise_fma(whi, fra, a23A);
                a01B = __builtin_elementwise_fma(wlo, frb, a01B);
                a23B = __builtin_elementwise_fma(whi, frb, a23B);
            }
        }
        const float inv_sqrt_c = 0.08838834764831845f;  // 1/sqrt(128)

        // node A = b0 + p
        {
            int bb = b0 + p;
            float a0 = a01A[0], a1 = a01A[1], a2 = a23A[0], a3 = a23A[1];
            if (isl0) {
                size_t o = (size_t)bb * 512 + j0;
                float4 s = *(const float4*)(sc + o);
                float4 rr;
                rr.x = a0 * inv_sqrt_c + s.x;
                rr.y = a1 * inv_sqrt_c + s.y;
                rr.z = a2 * inv_sqrt_c + s.z;
                rr.w = a3 * inv_sqrt_c + s.w;
                *(float4*)(out + o) = rr;
            } else {
                float av[4] = {a0, a1, a2, a3};
                #pragma unroll
                for (int jj = 0; jj < 4; jj++) {
                    size_t o = (size_t)bb * 512 + 128 + 3 * (j0 + jj) + m;
                    out[o] = av[jj] * inv_sqrt_c + sc[o];
                }
            }
        }
        // node B = b0 + p + 2
        {
            int bb = b0 + p + 2;
            float a0 = a01B[0], a1 = a01B[1], a2 = a23B[0], a3 = a23B[1];
            if (isl0) {
                size_t o = (size_t)bb * 512 + j0;
                float4 s = *(const float4*)(sc + o);
                float4 rr;
                rr.x = a0 * inv_sqrt_c + s.x;
                rr.y = a1 * inv_sqrt_c + s.y;
                rr.z = a2 * inv_sqrt_c + s.z;
                rr.w = a3 * inv_sqrt_c + s.w;
                *(float4*)(out + o) = rr;
            } else {
                float av[4] = {a0, a1, a2, a3};
                #pragma unroll
                for (int jj = 0; jj < 4; jj++) {
                    size_t o = (size_t)bb * 512 + 128 + 3 * (j0 + jj) + m;
                    out[o] = av[jj] * inv_sqrt_c + sc[o];
                }
            }
        }
    }
}

extern "C" void kernel_launch(void* const* d_in, const int* in_sizes, int n_in,
                              void* d_out, int out_size, void* d_ws, size_t ws_size,
                              hipStream_t stream) {
    const float* x     = (const float*)d_in[0];
    const float* y     = (const float*)d_in[1];
    const float* sc    = (const float*)d_in[2];
    const float* u3_l0 = (const float*)d_in[3];
    const float* u2_l0 = (const float*)d_in[4];
    const float* u1_l0 = (const float*)d_in[5];
    const float* w3_l0 = (const float*)d_in[6];
    const float* w2_l0 = (const float*)d_in[7];
    const float* w1_l0 = (const float*)d_in[8];
    const float* u3_l1 = (const float*)d_in[9];
    const float* u2_l1 = (const float*)d_in[10];
    const float* u1_l1 = (const float*)d_in[11];
    const float* w3_l1 = (const float*)d_in[12];
    const float* w2_l1 = (const float*)d_in[13];
    const float* w1_l1 = (const float*)d_in[14];
    const float* lw0   = (const float*)d_in[15];
    const float* lw1   = (const float*)d_in[16];
    float* out = (float*)d_out;

    // Workspace: Utab (f16, 14336 B) | us1f (fp32, 288 B)
    _Float16* Utab = (_Float16*)d_ws;
    float* us1f = (float*)((char*)d_ws + UTAB_HALVES * 2);

    build_utab_kernel<<<(UTAB_HALVES + 72 + 255) / 256, 256, 0, stream>>>(
        u3_l0, u2_l0, u1_l0, u3_l1, u2_l1, u1_l1, Utab, us1f);
    fused_kernel<<<N_NODES / 4, 256, 0, stream>>>(
        x, y, Utab, us1f,
        w3_l0, w2_l0, w1_l0, w3_l1, w2_l1, w1_l1,
        lw0, lw1, sc, out);
}